// Round 2
// baseline (920.671 us; speedup 1.0000x reference)
//
#include <hip/hip_runtime.h>
#include <hip/hip_bf16.h>

// Problem constants
#define BATCH  2
#define SEQ    2048
#define EMBED  1024
#define NHEADS 16
#define HDIM   64
#define SCALE  0.125f   // 1/sqrt(64)

typedef __attribute__((ext_vector_type(8))) short   short8;   // 8 bf16 = 4 VGPRs (MFMA A/B frag)
typedef __attribute__((ext_vector_type(4))) float   floatx4;  // MFMA C/D frag

__device__ __forceinline__ float bf2f(unsigned short h) {
    union { unsigned int u; float f; } v; v.u = ((unsigned int)h) << 16; return v.f;
}
__device__ __forceinline__ unsigned short f2bf(float f) {
    union { float f; unsigned int u; } v; v.f = f;
    unsigned int r = v.u + 0x7FFF + ((v.u >> 16) & 1);  // RNE
    return (unsigned short)(r >> 16);
}
__device__ __forceinline__ unsigned int pack2(float lo, float hi) {
    return (unsigned int)f2bf(lo) | ((unsigned int)f2bf(hi) << 16);
}

// ---------------------------------------------------------------------------
// C[M,N](bf16) = A[M,K](fp32) @ W[N,K]^T(fp32) + bias(fp32)
// 64x64 tile / 256-thread block / 4 waves, BK=64, mfma_f32_16x16x32_bf16.
// A-frag:  lane reads A[m = lane&15][k = (lane>>4)*8 + j]
// B-frag:  identical pattern on W rows (B^T form)
// C/D:     col = lane&15, row = (lane>>4)*4 + reg     (verified m89/m91)
// ---------------------------------------------------------------------------
__global__ __launch_bounds__(256)
void proj_gemm(const float* __restrict__ A, const float* __restrict__ W,
               const float* __restrict__ bias, unsigned short* __restrict__ C,
               int M, int N, int K)
{
    __shared__ unsigned short As[64][72];
    __shared__ unsigned short Bs[64][72];

    const int t    = threadIdx.x;
    const int w    = t >> 6;
    const int lane = t & 63;
    const int lr   = lane & 15;
    const int quad = lane >> 4;
    const int m0   = blockIdx.y * 64;
    const int n0   = blockIdx.x * 64;
    const int srow = t >> 2;
    const int sseg = (t & 3) * 16;

    floatx4 acc[4];
    #pragma unroll
    for (int i = 0; i < 4; ++i) acc[i] = (floatx4){0.f, 0.f, 0.f, 0.f};

    for (int k0 = 0; k0 < K; k0 += 64) {
        __syncthreads();
        {
            const float4* ap = (const float4*)(A + (size_t)(m0 + srow) * K + k0 + sseg);
            float4 a0 = ap[0], a1 = ap[1], a2 = ap[2], a3 = ap[3];
            const float4* bp = (const float4*)(W + (size_t)(n0 + srow) * K + k0 + sseg);
            float4 b0 = bp[0], b1 = bp[1], b2 = bp[2], b3 = bp[3];
            uint4 ua0 = {pack2(a0.x,a0.y), pack2(a0.z,a0.w), pack2(a1.x,a1.y), pack2(a1.z,a1.w)};
            uint4 ua1 = {pack2(a2.x,a2.y), pack2(a2.z,a2.w), pack2(a3.x,a3.y), pack2(a3.z,a3.w)};
            uint4 ub0 = {pack2(b0.x,b0.y), pack2(b0.z,b0.w), pack2(b1.x,b1.y), pack2(b1.z,b1.w)};
            uint4 ub1 = {pack2(b2.x,b2.y), pack2(b2.z,b2.w), pack2(b3.x,b3.y), pack2(b3.z,b3.w)};
            *(uint4*)&As[srow][sseg]     = ua0;
            *(uint4*)&As[srow][sseg + 8] = ua1;
            *(uint4*)&Bs[srow][sseg]     = ub0;
            *(uint4*)&Bs[srow][sseg + 8] = ub1;
        }
        __syncthreads();
        #pragma unroll
        for (int s = 0; s < 2; ++s) {
            short8 af = *(const short8*)&As[w * 16 + lr][s * 32 + quad * 8];
            #pragma unroll
            for (int nb = 0; nb < 4; ++nb) {
                short8 bf = *(const short8*)&Bs[nb * 16 + lr][s * 32 + quad * 8];
                acc[nb] = __builtin_amdgcn_mfma_f32_16x16x32_bf16(af, bf, acc[nb], 0, 0, 0);
            }
        }
    }

    #pragma unroll
    for (int nb = 0; nb < 4; ++nb) {
        const int col = n0 + nb * 16 + lr;
        const float bv = bias[col];
        #pragma unroll
        for (int r = 0; r < 4; ++r) {
            const int row = m0 + w * 16 + quad * 4 + r;
            C[(size_t)row * N + col] = f2bf(acc[nb][r] + bv);
        }
    }
}

// ---------------------------------------------------------------------------
// C[M,N](fp32) = A[M,K](bf16) @ W[N,K]^T(fp32) + bias(fp32)   (output proj)
// ---------------------------------------------------------------------------
__global__ __launch_bounds__(256)
void out_gemm(const unsigned short* __restrict__ A, const float* __restrict__ W,
              const float* __restrict__ bias, float* __restrict__ C,
              int M, int N, int K)
{
    __shared__ unsigned short As[64][72];
    __shared__ unsigned short Bs[64][72];

    const int t    = threadIdx.x;
    const int w    = t >> 6;
    const int lane = t & 63;
    const int lr   = lane & 15;
    const int quad = lane >> 4;
    const int m0   = blockIdx.y * 64;
    const int n0   = blockIdx.x * 64;
    const int srow = t >> 2;
    const int sseg = (t & 3) * 16;

    floatx4 acc[4];
    #pragma unroll
    for (int i = 0; i < 4; ++i) acc[i] = (floatx4){0.f, 0.f, 0.f, 0.f};

    for (int k0 = 0; k0 < K; k0 += 64) {
        __syncthreads();
        {
            const uint4* ap = (const uint4*)(A + (size_t)(m0 + srow) * K + k0 + sseg);
            uint4 ua0 = ap[0], ua1 = ap[1];
            const float4* bp = (const float4*)(W + (size_t)(n0 + srow) * K + k0 + sseg);
            float4 b0 = bp[0], b1 = bp[1], b2 = bp[2], b3 = bp[3];
            uint4 ub0 = {pack2(b0.x,b0.y), pack2(b0.z,b0.w), pack2(b1.x,b1.y), pack2(b1.z,b1.w)};
            uint4 ub1 = {pack2(b2.x,b2.y), pack2(b2.z,b2.w), pack2(b3.x,b3.y), pack2(b3.z,b3.w)};
            *(uint4*)&As[srow][sseg]     = ua0;
            *(uint4*)&As[srow][sseg + 8] = ua1;
            *(uint4*)&Bs[srow][sseg]     = ub0;
            *(uint4*)&Bs[srow][sseg + 8] = ub1;
        }
        __syncthreads();
        #pragma unroll
        for (int s = 0; s < 2; ++s) {
            short8 af = *(const short8*)&As[w * 16 + lr][s * 32 + quad * 8];
            #pragma unroll
            for (int nb = 0; nb < 4; ++nb) {
                short8 bf = *(const short8*)&Bs[nb * 16 + lr][s * 32 + quad * 8];
                acc[nb] = __builtin_amdgcn_mfma_f32_16x16x32_bf16(af, bf, acc[nb], 0, 0, 0);
            }
        }
    }

    #pragma unroll
    for (int nb = 0; nb < 4; ++nb) {
        const int col = n0 + nb * 16 + lr;
        const float bv = bias[col];
        #pragma unroll
        for (int r = 0; r < 4; ++r) {
            const int row = m0 + w * 16 + quad * 4 + r;
            C[(size_t)row * N + col] = acc[nb][r] + bv;
        }
    }
}

// ---------------------------------------------------------------------------
// Fused causal attention, one (b, h, 64-row q-tile) per block.
// Phase 1: online m,l over causal k-tiles (scores recomputed, never stored).
// Phase 2: recompute scores, p = exp(s-m)/l (final m,l so no rescaling),
//          write attn (fp32, coalesced via bf16 LDS repack), PV MFMA from the
//          same LDS tile. V staged transposed (Vt[d][k]) for the B^T pattern.
// ---------------------------------------------------------------------------
__global__ __launch_bounds__(256)
void attn_fused(const unsigned short* __restrict__ Qb,
                const unsigned short* __restrict__ Kb,
                const unsigned short* __restrict__ Vb,
                float* __restrict__ attn,           // [B,H,S,S] fp32
                unsigned short* __restrict__ AO)    // [B,S,E]   bf16
{
    __shared__ unsigned short Qs[64][72];
    __shared__ unsigned short Ks[64][72];
    __shared__ unsigned short Ps[64][72];
    __shared__ unsigned short Vt[64][72];  // Vt[d][k]

    const int t    = threadIdx.x;
    const int w    = t >> 6;
    const int lane = t & 63;
    const int lr   = lane & 15;
    const int quad = lane >> 4;
    const int qt   = blockIdx.x;
    const int h    = blockIdx.y;
    const int b    = blockIdx.z;
    const int q0   = qt * 64;
    const int srow = t >> 2;
    const int sseg = (t & 3) * 16;

    const size_t kvbase = (size_t)b * SEQ * EMBED + h * HDIM;

    // Stage Q tile once (first loop's second barrier covers visibility)
    {
        const uint4* qp = (const uint4*)(Qb + kvbase + (size_t)(q0 + srow) * EMBED + sseg);
        uint4 a0 = qp[0], a1 = qp[1];
        *(uint4*)&Qs[srow][sseg]     = a0;
        *(uint4*)&Qs[srow][sseg + 8] = a1;
    }

    float mrow[4], lsum[4];
    #pragma unroll
    for (int r = 0; r < 4; ++r) { mrow[r] = -1e30f; lsum[r] = 0.f; }

    // ---------------- Phase 1: m, l ----------------
    for (int kt = 0; kt <= qt; ++kt) {
        const int k0 = kt * 64;
        __syncthreads();
        {
            const uint4* kp = (const uint4*)(Kb + kvbase + (size_t)(k0 + srow) * EMBED + sseg);
            uint4 a0 = kp[0], a1 = kp[1];
            *(uint4*)&Ks[srow][sseg]     = a0;
            *(uint4*)&Ks[srow][sseg + 8] = a1;
        }
        __syncthreads();

        floatx4 sf[4];
        #pragma unroll
        for (int i = 0; i < 4; ++i) sf[i] = (floatx4){0.f, 0.f, 0.f, 0.f};
        #pragma unroll
        for (int s = 0; s < 2; ++s) {
            short8 af = *(const short8*)&Qs[w * 16 + lr][s * 32 + quad * 8];
            #pragma unroll
            for (int nb = 0; nb < 4; ++nb) {
                short8 bf = *(const short8*)&Ks[nb * 16 + lr][s * 32 + quad * 8];
                sf[nb] = __builtin_amdgcn_mfma_f32_16x16x32_bf16(af, bf, sf[nb], 0, 0, 0);
            }
        }

        #pragma unroll
        for (int r = 0; r < 4; ++r) {
            const int q = q0 + w * 16 + quad * 4 + r;
            float sv[4];
            float smax = -1e30f;
            #pragma unroll
            for (int nb = 0; nb < 4; ++nb) {
                const int k = k0 + nb * 16 + lr;
                float x = sf[nb][r] * SCALE;
                if (k > q) x = -1e30f;   // causal mask (bites only on diagonal tile)
                sv[nb] = x;
                smax = fmaxf(smax, x);
            }
            #pragma unroll
            for (int off = 1; off < 16; off <<= 1)
                smax = fmaxf(smax, __shfl_xor(smax, off, 64));
            const float mnew = fmaxf(mrow[r], smax);
            float es = 0.f;
            #pragma unroll
            for (int nb = 0; nb < 4; ++nb) es += __expf(sv[nb] - mnew);
            #pragma unroll
            for (int off = 1; off < 16; off <<= 1)
                es += __shfl_xor(es, off, 64);
            lsum[r] = lsum[r] * __expf(mrow[r] - mnew) + es;
            mrow[r] = mnew;
        }
    }

    float invl[4];
    #pragma unroll
    for (int r = 0; r < 4; ++r) invl[r] = 1.f / lsum[r];

    // ---------------- Phase 2: attn write + PV ----------------
    floatx4 of[4];
    #pragma unroll
    for (int i = 0; i < 4; ++i) of[i] = (floatx4){0.f, 0.f, 0.f, 0.f};

    float* attn_bh = attn + ((size_t)(b * NHEADS + h)) * SEQ * SEQ;

    for (int kt = 0; kt < SEQ / 64; ++kt) {
        const int k0 = kt * 64;
        if (kt <= qt) {
            __syncthreads();
            {
                const uint4* kp = (const uint4*)(Kb + kvbase + (size_t)(k0 + srow) * EMBED + sseg);
                uint4 a0 = kp[0], a1 = kp[1];
                *(uint4*)&Ks[srow][sseg]     = a0;
                *(uint4*)&Ks[srow][sseg + 8] = a1;
            }
            // V staged transposed: Vt[d][k]
            #pragma unroll
            for (int i = 0; i < 2; ++i) {
                const int u    = t + i * 256;
                const int kr   = u & 63;
                const int dseg = u >> 6;   // 0..7
                const uint4 vv = *(const uint4*)(Vb + kvbase + (size_t)(k0 + kr) * EMBED + dseg * 8);
                const unsigned short* pv = (const unsigned short*)&vv;
                #pragma unroll
                for (int j = 0; j < 8; ++j) Vt[dseg * 8 + j][kr] = pv[j];
            }
            __syncthreads();

            // Recompute scores
            floatx4 sf[4];
            #pragma unroll
            for (int i = 0; i < 4; ++i) sf[i] = (floatx4){0.f, 0.f, 0.f, 0.f};
            #pragma unroll
            for (int s = 0; s < 2; ++s) {
                short8 af = *(const short8*)&Qs[w * 16 + lr][s * 32 + quad * 8];
                #pragma unroll
                for (int nb = 0; nb < 4; ++nb) {
                    short8 bf = *(const short8*)&Ks[nb * 16 + lr][s * 32 + quad * 8];
                    sf[nb] = __builtin_amdgcn_mfma_f32_16x16x32_bf16(af, bf, sf[nb], 0, 0, 0);
                }
            }

            // p = exp(s - m) / l  → Ps (LDS, A-layout for PV + coalesced write)
            #pragma unroll
            for (int nb = 0; nb < 4; ++nb) {
                const int k = k0 + nb * 16 + lr;
                #pragma unroll
                for (int r = 0; r < 4; ++r) {
                    const int q = q0 + w * 16 + quad * 4 + r;
                    float p = 0.f;
                    if (k <= q) p = __expf(sf[nb][r] * SCALE - mrow[r]) * invl[r];
                    Ps[w * 16 + quad * 4 + r][nb * 16 + lr] = f2bf(p);
                }
            }
            __syncthreads();

            // Coalesced fp32 attn tile write (expand bf16 P)
            {
                const unsigned short* ps = &Ps[srow][sseg];
                float* op = attn_bh + (size_t)(q0 + srow) * SEQ + k0 + sseg;
                #pragma unroll
                for (int g = 0; g < 4; ++g) {
                    float4 f;
                    f.x = bf2f(ps[g * 4 + 0]);
                    f.y = bf2f(ps[g * 4 + 1]);
                    f.z = bf2f(ps[g * 4 + 2]);
                    f.w = bf2f(ps[g * 4 + 3]);
                    ((float4*)op)[g] = f;
                }
            }

            // PV: O += P @ V   (A-frag from Ps, B-frag from Vt)
            #pragma unroll
            for (int s = 0; s < 2; ++s) {
                short8 af = *(const short8*)&Ps[w * 16 + lr][s * 32 + quad * 8];
                #pragma unroll
                for (int nb = 0; nb < 4; ++nb) {
                    short8 bf = *(const short8*)&Vt[nb * 16 + lr][s * 32 + quad * 8];
                    of[nb] = __builtin_amdgcn_mfma_f32_16x16x32_bf16(af, bf, of[nb], 0, 0, 0);
                }
            }
        } else {
            // Strictly-masked tile: attn is exactly 0
            float4 z = {0.f, 0.f, 0.f, 0.f};
            float* op = attn_bh + (size_t)(q0 + srow) * SEQ + k0 + sseg;
            #pragma unroll
            for (int g = 0; g < 4; ++g) ((float4*)op)[g] = z;
        }
    }

    // O → AO (bf16 ws) in [B,S,E] layout (row = q, col = h*64 + d)
    #pragma unroll
    for (int nb = 0; nb < 4; ++nb) {
        #pragma unroll
        for (int r = 0; r < 4; ++r) {
            const int q = q0 + w * 16 + quad * 4 + r;
            const int d = nb * 16 + lr;
            AO[(size_t)(b * SEQ + q) * EMBED + h * HDIM + d] = f2bf(of[nb][r]);
        }
    }
}

// ---------------------------------------------------------------------------
extern "C" void kernel_launch(void* const* d_in, const int* in_sizes, int n_in,
                              void* d_out, int out_size, void* d_ws, size_t ws_size,
                              hipStream_t stream)
{
    const float* query = (const float*)d_in[0];
    const float* key   = (const float*)d_in[1];
    const float* value = (const float*)d_in[2];
    const float* Wq    = (const float*)d_in[3];
    const float* bq    = (const float*)d_in[4];
    const float* Wk    = (const float*)d_in[5];
    const float* bk    = (const float*)d_in[6];
    const float* Wv    = (const float*)d_in[7];
    const float* bv    = (const float*)d_in[8];
    const float* Wo    = (const float*)d_in[9];
    const float* bo    = (const float*)d_in[10];

    float* out  = (float*)d_out;                              // [B,S,E]
    float* attn = out + (size_t)BATCH * SEQ * EMBED;          // [B,H,S,S]

    const size_t tsz = (size_t)BATCH * SEQ * EMBED;           // 4 Mi elements
    unsigned short* Qb = (unsigned short*)d_ws;
    unsigned short* Kb = Qb + tsz;
    unsigned short* Vb = Kb + tsz;
    unsigned short* AO = Vb + tsz;                            // 32 MiB of ws total

    const dim3 blk(256);
    const dim3 gproj(EMBED / 64, (BATCH * SEQ) / 64);         // (16, 64)

    proj_gemm<<<gproj, blk, 0, stream>>>(query, Wq, bq, Qb, BATCH * SEQ, EMBED, EMBED);
    proj_gemm<<<gproj, blk, 0, stream>>>(key,   Wk, bk, Kb, BATCH * SEQ, EMBED, EMBED);
    proj_gemm<<<gproj, blk, 0, stream>>>(value, Wv, bv, Vb, BATCH * SEQ, EMBED, EMBED);

    attn_fused<<<dim3(SEQ / 64, NHEADS, BATCH), blk, 0, stream>>>(Qb, Kb, Vb, attn, AO);

    out_gemm<<<gproj, blk, 0, stream>>>(AO, Wo, bo, out, BATCH * SEQ, EMBED, EMBED);
}

// Round 3
// 862.468 us; speedup vs baseline: 1.0675x; 1.0675x over previous
//
#include <hip/hip_runtime.h>
#include <hip/hip_bf16.h>

// Problem constants
#define BATCH  2
#define SEQ    2048
#define EMBED  1024
#define NHEADS 16
#define HDIM   64
#define SCALE  0.125f                 // 1/sqrt(64)
#define S2     0.180336880f           // SCALE * log2(e): score*S2 is in exp2 domain

typedef __attribute__((ext_vector_type(8))) short   short8;   // 8 bf16 = 4 VGPRs (MFMA A/B frag)
typedef __attribute__((ext_vector_type(4))) float   floatx4;  // MFMA C/D frag

#if __has_builtin(__builtin_amdgcn_exp2f)
#define EXP2(x) __builtin_amdgcn_exp2f(x)
#else
#define EXP2(x) exp2f(x)
#endif

// async global->LDS, 16B per lane; LDS dest = uniform base + lane*16
#define GLOAD_LDS(g, l) __builtin_amdgcn_global_load_lds(                      \
    (const __attribute__((address_space(1))) void*)(const void*)(g),           \
    (__attribute__((address_space(3))) void*)(void*)(l), 16, 0, 0)

__device__ __forceinline__ float bf2f(unsigned short h) {
    union { unsigned int u; float f; } v; v.u = ((unsigned int)h) << 16; return v.f;
}
__device__ __forceinline__ unsigned short f2bf(float f) {
    union { float f; unsigned int u; } v; v.f = f;
    unsigned int r = v.u + 0x7FFF + ((v.u >> 16) & 1);  // RNE
    return (unsigned short)(r >> 16);
}
__device__ __forceinline__ unsigned int pack2(float lo, float hi) {
    return (unsigned int)f2bf(lo) | ((unsigned int)f2bf(hi) << 16);
}

// ---------------------------------------------------------------------------
// One-shot fp32 -> bf16 conversion: 3 big tensors (B*S*E) + 4 weights (E*E).
// 8 floats per thread, 16B bf16 stores. grid = (2048, 7).
// ---------------------------------------------------------------------------
__global__ __launch_bounds__(256)
void cvt_bf16(const float* __restrict__ q,  const float* __restrict__ k,
              const float* __restrict__ v,  const float* __restrict__ wq,
              const float* __restrict__ wk, const float* __restrict__ wv,
              const float* __restrict__ wo,
              unsigned short* __restrict__ dq,  unsigned short* __restrict__ dk,
              unsigned short* __restrict__ dv,  unsigned short* __restrict__ dwq,
              unsigned short* __restrict__ dwk, unsigned short* __restrict__ dwv,
              unsigned short* __restrict__ dwo)
{
    const float* s; unsigned short* d; int n;
    switch (blockIdx.y) {
        case 0: s = q;  d = dq;  n = BATCH * SEQ * EMBED; break;
        case 1: s = k;  d = dk;  n = BATCH * SEQ * EMBED; break;
        case 2: s = v;  d = dv;  n = BATCH * SEQ * EMBED; break;
        case 3: s = wq; d = dwq; n = EMBED * EMBED; break;
        case 4: s = wk; d = dwk; n = EMBED * EMBED; break;
        case 5: s = wv; d = dwv; n = EMBED * EMBED; break;
        default: s = wo; d = dwo; n = EMBED * EMBED; break;
    }
    const int i = (blockIdx.x * 256 + threadIdx.x) * 8;
    if (i >= n) return;
    float4 f0 = ((const float4*)(s + i))[0];
    float4 f1 = ((const float4*)(s + i))[1];
    uint4 u = {pack2(f0.x, f0.y), pack2(f0.z, f0.w),
               pack2(f1.x, f1.y), pack2(f1.z, f1.w)};
    *(uint4*)(d + i) = u;
}

// ---------------------------------------------------------------------------
// C[M,N] = A[M,K](bf16) @ W[N,K]^T(bf16) + bias(fp32); out bf16 or fp32.
// 128x64 tile / 256 threads / 4 waves (wave w owns rows w*32..w*32+31).
// BK=64. Staging via global_load_lds width-16 (m97 structure) into UNPADDED
// LDS tiles; 16B k-groups XOR-swizzled by (row&7) so frag ds_read_b128 is
// 2-way bank aliased (free) instead of 16-way. Swizzle is possible because
// the global source address is per-lane while the LDS dest is lane-ordered.
// C/D: col = lane&15, row = (lane>>4)*4 + reg  (verified m89/m91).
// ---------------------------------------------------------------------------
__global__ __launch_bounds__(256)
void gemm128(const unsigned short* __restrict__ A,
             const unsigned short* __restrict__ W,
             const float* __restrict__ bias,
             void* __restrict__ Cout, int f32out,
             int M, int N, int K)
{
    __shared__ unsigned short As[128 * 64];   // 16 KB
    __shared__ unsigned short Bs[64 * 64];    //  8 KB

    const int t    = threadIdx.x;
    const int w    = t >> 6;
    const int lane = t & 63;
    const int lr   = lane & 15;
    const int quad = lane >> 4;
    const int n0   = blockIdx.x * 64;
    const int m0   = blockIdx.y * 128;

    // Per-lane global element offsets for the staging issues.
    // A tile: 1024 16B slots; issue i of wave w covers slots i*256+w*64+lane.
    // slot -> row = slot>>3, stored-group p = slot&7, global group g = p^(row&7).
    size_t agoff[4];
    #pragma unroll
    for (int i = 0; i < 4; ++i) {
        const int slot = i * 256 + w * 64 + lane;
        const int row  = slot >> 3;
        const int g    = (slot & 7) ^ (row & 7);
        agoff[i] = (size_t)(m0 + row) * K + g * 8;
    }
    size_t bgoff[2];
    #pragma unroll
    for (int i = 0; i < 2; ++i) {
        const int slot = i * 256 + w * 64 + lane;
        const int row  = slot >> 3;
        const int g    = (slot & 7) ^ (row & 7);
        bgoff[i] = (size_t)(n0 + row) * K + g * 8;
    }

    // LDS fragment pointers (constant across k-tiles).
    const short8* apf[2][2];
    #pragma unroll
    for (int mb = 0; mb < 2; ++mb)
        #pragma unroll
        for (int s = 0; s < 2; ++s) {
            const int row = w * 32 + mb * 16 + lr;
            apf[mb][s] = (const short8*)&As[row * 64 + (((s * 4 + quad) ^ (row & 7)) * 8)];
        }
    const short8* bpf[4][2];
    #pragma unroll
    for (int nb = 0; nb < 4; ++nb)
        #pragma unroll
        for (int s = 0; s < 2; ++s) {
            const int row = nb * 16 + lr;
            bpf[nb][s] = (const short8*)&Bs[row * 64 + (((s * 4 + quad) ^ (row & 7)) * 8)];
        }

    floatx4 acc[2][4];
    #pragma unroll
    for (int mb = 0; mb < 2; ++mb)
        #pragma unroll
        for (int nb = 0; nb < 4; ++nb) acc[mb][nb] = (floatx4){0.f, 0.f, 0.f, 0.f};

    for (int k0 = 0; k0 < K; k0 += 64) {
        __syncthreads();
        #pragma unroll
        for (int i = 0; i < 4; ++i)
            GLOAD_LDS(A + agoff[i] + k0, &As[(i * 256 + w * 64) * 8]);
        #pragma unroll
        for (int i = 0; i < 2; ++i)
            GLOAD_LDS(W + bgoff[i] + k0, &Bs[(i * 256 + w * 64) * 8]);
        __syncthreads();

        #pragma unroll
        for (int s = 0; s < 2; ++s) {
            short8 a0 = *apf[0][s];
            short8 a1 = *apf[1][s];
            #pragma unroll
            for (int nb = 0; nb < 4; ++nb) {
                short8 bf = *bpf[nb][s];
                acc[0][nb] = __builtin_amdgcn_mfma_f32_16x16x32_bf16(a0, bf, acc[0][nb], 0, 0, 0);
                acc[1][nb] = __builtin_amdgcn_mfma_f32_16x16x32_bf16(a1, bf, acc[1][nb], 0, 0, 0);
            }
        }
    }

    #pragma unroll
    for (int mb = 0; mb < 2; ++mb)
        #pragma unroll
        for (int nb = 0; nb < 4; ++nb) {
            const int col = n0 + nb * 16 + lr;
            const float bv = bias[col];
            #pragma unroll
            for (int r = 0; r < 4; ++r) {
                const int row = m0 + w * 32 + mb * 16 + quad * 4 + r;
                const float val = acc[mb][nb][r] + bv;
                if (f32out) ((float*)Cout)[(size_t)row * N + col] = val;
                else        ((unsigned short*)Cout)[(size_t)row * N + col] = f2bf(val);
            }
        }
}

// ---------------------------------------------------------------------------
// Fused causal attention, one (b, h, 64-row q-tile) per block.
// Phase 1: online m,l (base-2 domain) over causal k-tiles.
// Phase 2: recompute scores, p = exp2(s*S2 - m)*invl, write attn fp32
//          (coalesced via bf16 LDS repack), PV MFMA from the same LDS tile.
// ---------------------------------------------------------------------------
__global__ __launch_bounds__(256)
void attn_fused(const unsigned short* __restrict__ Qb,
                const unsigned short* __restrict__ Kb,
                const unsigned short* __restrict__ Vb,
                float* __restrict__ attn,           // [B,H,S,S] fp32
                unsigned short* __restrict__ AO)    // [B,S,E]   bf16
{
    __shared__ unsigned short Qs[64][72];
    __shared__ unsigned short Ks[64][72];
    __shared__ unsigned short Ps[64][72];
    __shared__ unsigned short Vt[64][72];  // Vt[d][k]

    const int t    = threadIdx.x;
    const int w    = t >> 6;
    const int lane = t & 63;
    const int lr   = lane & 15;
    const int quad = lane >> 4;
    const int qt   = blockIdx.x;
    const int h    = blockIdx.y;
    const int b    = blockIdx.z;
    const int q0   = qt * 64;
    const int srow = t >> 2;
    const int sseg = (t & 3) * 16;

    const size_t kvbase = (size_t)b * SEQ * EMBED + h * HDIM;

    // Stage Q tile once (first loop's second barrier covers visibility)
    {
        const uint4* qp = (const uint4*)(Qb + kvbase + (size_t)(q0 + srow) * EMBED + sseg);
        uint4 a0 = qp[0], a1 = qp[1];
        *(uint4*)&Qs[srow][sseg]     = a0;
        *(uint4*)&Qs[srow][sseg + 8] = a1;
    }

    float mrow[4], lsum[4];
    #pragma unroll
    for (int r = 0; r < 4; ++r) { mrow[r] = -1e30f; lsum[r] = 0.f; }

    // ---------------- Phase 1: m, l ----------------
    for (int kt = 0; kt <= qt; ++kt) {
        const int k0 = kt * 64;
        __syncthreads();
        {
            const uint4* kp = (const uint4*)(Kb + kvbase + (size_t)(k0 + srow) * EMBED + sseg);
            uint4 a0 = kp[0], a1 = kp[1];
            *(uint4*)&Ks[srow][sseg]     = a0;
            *(uint4*)&Ks[srow][sseg + 8] = a1;
        }
        __syncthreads();

        floatx4 sf[4];
        #pragma unroll
        for (int i = 0; i < 4; ++i) sf[i] = (floatx4){0.f, 0.f, 0.f, 0.f};
        #pragma unroll
        for (int s = 0; s < 2; ++s) {
            short8 af = *(const short8*)&Qs[w * 16 + lr][s * 32 + quad * 8];
            #pragma unroll
            for (int nb = 0; nb < 4; ++nb) {
                short8 bf = *(const short8*)&Ks[nb * 16 + lr][s * 32 + quad * 8];
                sf[nb] = __builtin_amdgcn_mfma_f32_16x16x32_bf16(af, bf, sf[nb], 0, 0, 0);
            }
        }

        #pragma unroll
        for (int r = 0; r < 4; ++r) {
            const int q = q0 + w * 16 + quad * 4 + r;
            float sv[4];
            float smax = -1e30f;
            #pragma unroll
            for (int nb = 0; nb < 4; ++nb) {
                const int k = k0 + nb * 16 + lr;
                float x = sf[nb][r] * S2;            // exp2 domain
                if (k > q) x = -1e30f;               // causal mask
                sv[nb] = x;
                smax = fmaxf(smax, x);
            }
            #pragma unroll
            for (int off = 1; off < 16; off <<= 1)
                smax = fmaxf(smax, __shfl_xor(smax, off, 64));
            const float mnew = fmaxf(mrow[r], smax);
            float es = 0.f;
            #pragma unroll
            for (int nb = 0; nb < 4; ++nb) es += EXP2(sv[nb] - mnew);
            #pragma unroll
            for (int off = 1; off < 16; off <<= 1)
                es += __shfl_xor(es, off, 64);
            lsum[r] = lsum[r] * EXP2(mrow[r] - mnew) + es;
            mrow[r] = mnew;
        }
    }

    float invl[4];
    #pragma unroll
    for (int r = 0; r < 4; ++r) invl[r] = 1.f / lsum[r];

    // ---------------- Phase 2: attn write + PV ----------------
    floatx4 of[4];
    #pragma unroll
    for (int i = 0; i < 4; ++i) of[i] = (floatx4){0.f, 0.f, 0.f, 0.f};

    float* attn_bh = attn + ((size_t)(b * NHEADS + h)) * SEQ * SEQ;

    for (int kt = 0; kt < SEQ / 64; ++kt) {
        const int k0 = kt * 64;
        if (kt <= qt) {
            __syncthreads();
            {
                const uint4* kp = (const uint4*)(Kb + kvbase + (size_t)(k0 + srow) * EMBED + sseg);
                uint4 a0 = kp[0], a1 = kp[1];
                *(uint4*)&Ks[srow][sseg]     = a0;
                *(uint4*)&Ks[srow][sseg + 8] = a1;
            }
            // V staged transposed: Vt[d][k]
            #pragma unroll
            for (int i = 0; i < 2; ++i) {
                const int u    = t + i * 256;
                const int kr   = u & 63;
                const int dseg = u >> 6;   // 0..7
                const uint4 vv = *(const uint4*)(Vb + kvbase + (size_t)(k0 + kr) * EMBED + dseg * 8);
                const unsigned short* pv = (const unsigned short*)&vv;
                #pragma unroll
                for (int j = 0; j < 8; ++j) Vt[dseg * 8 + j][kr] = pv[j];
            }
            __syncthreads();

            // Recompute scores
            floatx4 sf[4];
            #pragma unroll
            for (int i = 0; i < 4; ++i) sf[i] = (floatx4){0.f, 0.f, 0.f, 0.f};
            #pragma unroll
            for (int s = 0; s < 2; ++s) {
                short8 af = *(const short8*)&Qs[w * 16 + lr][s * 32 + quad * 8];
                #pragma unroll
                for (int nb = 0; nb < 4; ++nb) {
                    short8 bf = *(const short8*)&Ks[nb * 16 + lr][s * 32 + quad * 8];
                    sf[nb] = __builtin_amdgcn_mfma_f32_16x16x32_bf16(af, bf, sf[nb], 0, 0, 0);
                }
            }

            // p = exp2(s*S2 - m) * invl  -> Ps (LDS, A-layout for PV + write)
            #pragma unroll
            for (int nb = 0; nb < 4; ++nb) {
                const int k = k0 + nb * 16 + lr;
                #pragma unroll
                for (int r = 0; r < 4; ++r) {
                    const int q = q0 + w * 16 + quad * 4 + r;
                    float p = 0.f;
                    if (k <= q) p = EXP2(sf[nb][r] * S2 - mrow[r]) * invl[r];
                    Ps[w * 16 + quad * 4 + r][nb * 16 + lr] = f2bf(p);
                }
            }
            __syncthreads();

            // Coalesced fp32 attn tile write (expand bf16 P)
            {
                const unsigned short* ps = &Ps[srow][sseg];
                float* op = attn_bh + (size_t)(q0 + srow) * SEQ + k0 + sseg;
                #pragma unroll
                for (int g = 0; g < 4; ++g) {
                    float4 f;
                    f.x = bf2f(ps[g * 4 + 0]);
                    f.y = bf2f(ps[g * 4 + 1]);
                    f.z = bf2f(ps[g * 4 + 2]);
                    f.w = bf2f(ps[g * 4 + 3]);
                    ((float4*)op)[g] = f;
                }
            }

            // PV: O += P @ V   (A-frag from Ps, B-frag from Vt)
            #pragma unroll
            for (int s = 0; s < 2; ++s) {
                short8 af = *(const short8*)&Ps[w * 16 + lr][s * 32 + quad * 8];
                #pragma unroll
                for (int nb = 0; nb < 4; ++nb) {
                    short8 bf = *(const short8*)&Vt[nb * 16 + lr][s * 32 + quad * 8];
                    of[nb] = __builtin_amdgcn_mfma_f32_16x16x32_bf16(af, bf, of[nb], 0, 0, 0);
                }
            }
        } else {
            // Strictly-masked tile: attn is exactly 0
            float4 z = {0.f, 0.f, 0.f, 0.f};
            float* op = attn_bh + (size_t)(q0 + srow) * SEQ + k0 + sseg;
            #pragma unroll
            for (int g = 0; g < 4; ++g) ((float4*)op)[g] = z;
        }
    }

    // O -> AO (bf16 ws) in [B,S,E] layout (row = q, col = h*64 + d)
    #pragma unroll
    for (int nb = 0; nb < 4; ++nb) {
        #pragma unroll
        for (int r = 0; r < 4; ++r) {
            const int q = q0 + w * 16 + quad * 4 + r;
            const int d = nb * 16 + lr;
            AO[(size_t)(b * SEQ + q) * EMBED + h * HDIM + d] = f2bf(of[nb][r]);
        }
    }
}

// ---------------------------------------------------------------------------
extern "C" void kernel_launch(void* const* d_in, const int* in_sizes, int n_in,
                              void* d_out, int out_size, void* d_ws, size_t ws_size,
                              hipStream_t stream)
{
    const float* query = (const float*)d_in[0];
    const float* key   = (const float*)d_in[1];
    const float* value = (const float*)d_in[2];
    const float* Wq    = (const float*)d_in[3];
    const float* bq    = (const float*)d_in[4];
    const float* Wk    = (const float*)d_in[5];
    const float* bk    = (const float*)d_in[6];
    const float* Wv    = (const float*)d_in[7];
    const float* bv    = (const float*)d_in[8];
    const float* Wo    = (const float*)d_in[9];
    const float* bo    = (const float*)d_in[10];

    float* out  = (float*)d_out;                              // [B,S,E]
    float* attn = out + (size_t)BATCH * SEQ * EMBED;          // [B,H,S,S]

    const size_t tsz = (size_t)BATCH * SEQ * EMBED;           // 4.19M elems
    const size_t wsz = (size_t)EMBED * EMBED;                 // 1.05M elems
    unsigned short* p = (unsigned short*)d_ws;
    unsigned short* xq  = p;  p += tsz;
    unsigned short* xk  = p;  p += tsz;
    unsigned short* xv  = p;  p += tsz;
    unsigned short* wq16 = p; p += wsz;
    unsigned short* wk16 = p; p += wsz;
    unsigned short* wv16 = p; p += wsz;
    unsigned short* wo16 = p; p += wsz;
    unsigned short* Qb  = p;  p += tsz;
    unsigned short* Kb  = p;  p += tsz;
    unsigned short* Vb  = p;  p += tsz;
    unsigned short* AO  = p;  p += tsz;   // ~67 MB total

    const dim3 blk(256);

    cvt_bf16<<<dim3(2048, 7), blk, 0, stream>>>(query, key, value, Wq, Wk, Wv, Wo,
                                                xq, xk, xv, wq16, wk16, wv16, wo16);

    const dim3 gproj(EMBED / 64, (BATCH * SEQ) / 128);        // (16, 32) = 512 blocks
    gemm128<<<gproj, blk, 0, stream>>>(xq, wq16, bq, Qb, 0, BATCH * SEQ, EMBED, EMBED);
    gemm128<<<gproj, blk, 0, stream>>>(xk, wk16, bk, Kb, 0, BATCH * SEQ, EMBED, EMBED);
    gemm128<<<gproj, blk, 0, stream>>>(xv, wv16, bv, Vb, 0, BATCH * SEQ, EMBED, EMBED);

    attn_fused<<<dim3(SEQ / 64, NHEADS, BATCH), blk, 0, stream>>>(Qb, Kb, Vb, attn, AO);

    gemm128<<<gproj, blk, 0, stream>>>(AO, wo16, bo, out, 1, BATCH * SEQ, EMBED, EMBED);
}